// Round 6
// baseline (716.944 us; speedup 1.0000x reference)
//
#include <hip/hip_runtime.h>
#include <hip/hip_bf16.h>

// ---------------------------------------------------------------------------
// KV-cached MHA, MI355X. Round 6:
//  * gemm8, prep: ROUND-4 VERBATIM (best measured: qkv 141us, out ~46us).
//  * attn_k rebuilt: KVBLK=64 (round-2's verified compute), 40KB LDS ->
//    4 blocks/CU, whole 1024-block grid co-resident; per-CU 4 blocks share
//    one (b,h) with qb {k,15-k,7-k,8+k} (balanced 34 trips); per-XCD 8 heads
//    = 4MB K/V exactly L2-resident. Async-stage split: next trip's K/V
//    global loads issued after staging barrier (fly under compute).
//    V chunk XOR swizzle (phys = lc ^ (d&7)): PV reads conflict-free.
// ---------------------------------------------------------------------------

typedef __bf16 bf16x8 __attribute__((ext_vector_type(8)));
typedef unsigned short u16x8 __attribute__((ext_vector_type(8)));
typedef float  f32x4  __attribute__((ext_vector_type(4)));
typedef unsigned int u32;

#define MFMA16(a, b, c) __builtin_amdgcn_mfma_f32_16x16x32_bf16((a), (b), (c), 0, 0, 0)

__device__ __forceinline__ void async16(__bf16* lds_p, const __bf16* g) {
    __builtin_amdgcn_global_load_lds(
        (__attribute__((address_space(1))) void*)g,
        (__attribute__((address_space(3))) void*)lds_p, 16, 0, 0);
}

// ---------------------------------------------------------------------------
// prep: one grid-stride BW pass (round-4 verbatim).
// ---------------------------------------------------------------------------
__global__ __launch_bounds__(256) void prep(
    const float* __restrict__ q, const float* __restrict__ k, const float* __restrict__ v,
    const float* __restrict__ wq, const float* __restrict__ wk,
    const float* __restrict__ wv, const float* __restrict__ wo,
    const float* __restrict__ ck, const float* __restrict__ cv,
    float* __restrict__ nk, float* __restrict__ nv,
    __bf16* __restrict__ dq, __bf16* __restrict__ dk, __bf16* __restrict__ dv,
    __bf16* __restrict__ dwq, __bf16* __restrict__ dwk,
    __bf16* __restrict__ dwv, __bf16* __restrict__ dwo,
    __bf16* __restrict__ ckb, __bf16* __restrict__ cvb) {
    const int nthreads = gridDim.x * blockDim.x;
    for (int i = blockIdx.x * blockDim.x + threadIdx.x; i < 7340032; i += nthreads) {
        if (i < 2097152) {
            const int sel = i >> 20;
            const int j = i & 1048575;
            const int dh8 = j & 15;
            const int t = (j >> 4) & 1023;
            const int h = (j >> 14) & 15;
            const int b = j >> 18;
            const float* src = sel ? cv : ck;
            float* dst = sel ? nv : nk;
            __bf16* dstb = sel ? cvb : ckb;
            const size_t si = ((size_t)(b << 10) + t) * 2048 + (h << 7) + (dh8 << 3);
            const size_t di = ((size_t)b << 22) + ((size_t)h << 18) + (t << 7) + (dh8 << 3);
            const size_t bi = (((size_t)(b * 16 + h) * 1024 + t) << 7) + (dh8 << 3);
            const f32x4 x0 = *(const f32x4*)&src[si];
            const f32x4 x1 = *(const f32x4*)&src[si + 4];
            *(f32x4*)&dst[di] = x0;
            *(f32x4*)&dst[di + 4] = x1;
            bf16x8 bx;
#pragma unroll
            for (int e = 0; e < 4; e++) {
                bx[e]     = (__bf16)x0[e];
                bx[e + 4] = (__bf16)x1[e];
            }
            *(bf16x8*)&dstb[bi] = bx;
        } else {
            const float* s;
            __bf16* d;
            int off;
            if (i < 5242880) {
                const int ii = i - 2097152;
                const int r = ii >> 20;
                off = ii & 1048575;
                s = (r == 0) ? q : (r == 1) ? k : v;
                d = (r == 0) ? dq : (r == 1) ? dk : dv;
            } else {
                const int ii = i - 5242880;
                const int r = ii >> 19;
                off = ii & 524287;
                s = (r == 0) ? wq : (r == 1) ? wk : (r == 2) ? wv : wo;
                d = (r == 0) ? dwq : (r == 1) ? dwk : (r == 2) ? dwv : dwo;
            }
            const f32x4 x0 = *(const f32x4*)(s + (size_t)off * 8);
            const f32x4 x1 = *(const f32x4*)(s + (size_t)off * 8 + 4);
            bf16x8 o;
#pragma unroll
            for (int j2 = 0; j2 < 4; j2++) {
                o[j2]     = (__bf16)x0[j2];
                o[j2 + 4] = (__bf16)x1[j2];
            }
            *(bf16x8*)(d + (size_t)off * 8) = o;
        }
    }
}

// ---------------------------------------------------------------------------
// 128x256 8-phase GEMM (round-4 verbatim; best measured GEMM config).
// ---------------------------------------------------------------------------
template <int MODE>
__global__ __launch_bounds__(512, 2) void gemm8(
    const __bf16* __restrict__ A,
    const __bf16* __restrict__ W0, const __bf16* __restrict__ W1,
    const __bf16* __restrict__ W2,
    const float* __restrict__ bz0, const float* __restrict__ bz1,
    const float* __restrict__ bz2,
    void* __restrict__ C0, float* __restrict__ C1, float* __restrict__ C2) {
    extern __shared__ __bf16 lds[];
    constexpr int K = 2048;
    const int tid = threadIdx.x;
    const int w = tid >> 6, lane = tid & 63;
    const int wm = w >> 2, wn = w & 3;
    const int g = lane >> 4, c = lane & 15;

    const int lin = blockIdx.x;
    const int nb = lin & 7, mb = lin >> 3;
    const int m0 = mb << 7, n0 = nb << 8;
    const int seg = (MODE == 1) ? (mb >> 5) : 0;
    const __bf16* W = (MODE == 0 || seg == 0) ? W0 : (seg == 1) ? W1 : W2;
    const float* bias = (MODE == 0) ? bz0 : (seg == 0) ? bz0 : (seg == 1) ? bz1 : bz2;

    const __bf16* Ab = A + (size_t)m0 * K;
    const __bf16* Wb = W + (size_t)n0 * K;

    const int srow = lane >> 2;
    const int sch = (lane & 3) ^ (((lane >> 5) & 1) << 1);
    const int foff = c * 32 + ((g ^ ((c >> 3) << 1)) << 3);

    f32x4 acc[4][4] = {};

    auto stgA = [&](int T, int rg) {
#pragma unroll
        for (int u = 0; u < 2; u++) {
            const __bf16* gs = Ab + (size_t)(w * 16 + srow) * K + T * 64 + u * 32 + sch * 8;
            async16(&lds[rg * 24576 + (w * 2 + u) * 512], gs);
        }
    };
    auto stgB = [&](int T, int rg) {
#pragma unroll
        for (int u = 0; u < 4; u++) {
            const int rowblk = 2 * w + (u >> 1), kk = u & 1;
            const __bf16* gs = Wb + (size_t)(rowblk * 16 + srow) * K + T * 64 + kk * 32 + sch * 8;
            async16(&lds[rg * 24576 + 8192 + (w * 4 + u) * 512], gs);
        }
    };

    stgA(0, 0); stgB(0, 0);
    stgA(1, 1); stgB(1, 1);
    asm volatile("s_waitcnt vmcnt(6)" ::: "memory");
    asm volatile("s_barrier" ::: "memory");

    int rg = 0;
    for (int T = 0; T < 32; T++) {
        int rs = rg + 2; if (rs >= 3) rs -= 3;
        const int base = rg * 24576;
        bf16x8 fa[4], fb[4];

#pragma unroll
        for (int mi = 0; mi < 4; mi++)
            fa[mi] = *(const bf16x8*)&lds[base + ((wm * 4 + mi) * 2 + 0) * 512 + foff];
#pragma unroll
        for (int ni = 0; ni < 4; ni++)
            fb[ni] = *(const bf16x8*)&lds[base + 8192 + ((wn * 4 + ni) * 2 + 0) * 512 + foff];
        if (T < 30) stgA(T + 2, rs);
        asm volatile("s_barrier" ::: "memory");
        asm volatile("s_waitcnt lgkmcnt(0)" ::: "memory");
        __builtin_amdgcn_sched_barrier(0);
        __builtin_amdgcn_s_setprio(1);
#pragma unroll
        for (int mi = 0; mi < 4; mi++)
#pragma unroll
            for (int ni = 0; ni < 4; ni++)
                acc[mi][ni] = MFMA16(fa[mi], fb[ni], acc[mi][ni]);
        __builtin_amdgcn_s_setprio(0);
        asm volatile("s_barrier" ::: "memory");

#pragma unroll
        for (int mi = 0; mi < 4; mi++)
            fa[mi] = *(const bf16x8*)&lds[base + ((wm * 4 + mi) * 2 + 1) * 512 + foff];
#pragma unroll
        for (int ni = 0; ni < 4; ni++)
            fb[ni] = *(const bf16x8*)&lds[base + 8192 + ((wn * 4 + ni) * 2 + 1) * 512 + foff];
        if (T < 30) {
            stgB(T + 2, rs);
            asm volatile("s_waitcnt vmcnt(6)" ::: "memory");
        } else {
            asm volatile("s_waitcnt vmcnt(0)" ::: "memory");
        }
        asm volatile("s_barrier" ::: "memory");
        asm volatile("s_waitcnt lgkmcnt(0)" ::: "memory");
        __builtin_amdgcn_sched_barrier(0);
        __builtin_amdgcn_s_setprio(1);
#pragma unroll
        for (int mi = 0; mi < 4; mi++)
#pragma unroll
            for (int ni = 0; ni < 4; ni++)
                acc[mi][ni] = MFMA16(fa[mi], fb[ni], acc[mi][ni]);
        __builtin_amdgcn_s_setprio(0);
        asm volatile("s_barrier" ::: "memory");

        rg = (rg + 1 == 3) ? 0 : rg + 1;
    }

#pragma unroll
    for (int ni = 0; ni < 4; ni++) {
        const int col = n0 + wn * 64 + ni * 16 + c;
        const float bv = bias[col];
        const int h = col >> 7, dh = col & 127;
#pragma unroll
        for (int mi = 0; mi < 4; mi++) {
            const int rowb = m0 + wm * 64 + mi * 16 + g * 4;
#pragma unroll
            for (int r = 0; r < 4; r++) {
                const float v = acc[mi][ni][r] + bv;
                if (MODE == 0) {
                    ((float*)C0)[(size_t)(rowb + r) * 2048 + col] = v;
                } else {
                    const int lrow = (rowb + r) & 4095;
                    const int b = lrow >> 10, t = lrow & 1023;
                    if (seg == 0)
                        ((__bf16*)C0)[(((size_t)(b * 16 + h) * 1024) + t) * 128 + dh] = (__bf16)v;
                    else if (seg == 1)
                        C1[(((size_t)(b * 16 + h) * 2048) + 1024 + t) * 128 + dh] = v;
                    else
                        C2[(((size_t)(b * 16 + h) * 2048) + 1024 + t) * 128 + dh] = v;
                }
            }
        }
    }
}

// ---------------------------------------------------------------------------
// Flash attention, KVBLK=64. LDS exactly 40KB -> 4 blocks/CU, entire grid
// co-resident. Dispatch: xcd=lin&7, j=lin>>3, rr=j>>5, s=j&31;
// bh = xcd*8 + (s>>2) (8 heads/XCD = 4MB K/V, L2-resident); kq = s&3;
// qb = {kq, 15-kq, 7-kq, 8+kq}[rr] -> per-CU trips = 34 (exactly balanced).
// Kt [64][128] bf16, chunk-XOR swizzle (ch ^ row&7): writes ~2-way, reads free.
// Vt32 [128][32] u32 key-pairs, chunk-XOR (lc ^ d&7): reads free, writes 4-way.
// Pw per-wave [16][64], chunk swizzle. Async-stage: next trip's 8 global
// loads issued right after staging barrier, land during compute.
// ---------------------------------------------------------------------------
__global__ __launch_bounds__(256, 4) void attn_k(const __bf16* __restrict__ Qw,
                                                 const __bf16* __restrict__ cK,
                                                 const __bf16* __restrict__ cV,
                                                 __bf16* __restrict__ O) {
    __shared__ __bf16 Kt[64 * 128];     // 16 KB
    __shared__ u32    Vt32[128 * 32];   // 16 KB
    __shared__ __bf16 Pw[4][16 * 64];   // 8 KB

    const int tid = threadIdx.x;
    const int w = tid >> 6;
    const int lane = tid & 63;
    const int g = lane >> 4, c = lane & 15;

    const int lin = blockIdx.x + (blockIdx.y << 4) + (blockIdx.z << 8);
    const int xcd = lin & 7;
    const int j = lin >> 3;
    const int rr = j >> 5, s = j & 31;
    const int bh = xcd * 8 + (s >> 2);
    const int kq = s & 3;
    const int qb = (rr == 0) ? kq : (rr == 1) ? 15 - kq : (rr == 2) ? 7 - kq : 8 + kq;
    const int q0 = qb << 6;
    const float inv_scale = 0.08838834764831845f; // 1/sqrt(128)

    const __bf16* qbase = Qw + (((size_t)bh * 1024) + q0 + w * 16) * 128;
    bf16x8 qf[4];
#pragma unroll
    for (int dc = 0; dc < 4; dc++)
        qf[dc] = *(const bf16x8*)&qbase[c * 128 + dc * 32 + g * 8];

    f32x4 accO[8] = {};
    float m_run[4], l_run[4];
#pragma unroll
    for (int r = 0; r < 4; r++) { m_run[r] = -1e30f; l_run[r] = 0.0f; }

    const int trips = qb + 1;
    const __bf16* kb = cK + (size_t)bh * 1024 * 128;
    const __bf16* vb = cV + (size_t)bh * 1024 * 128;

    // K staging: thread owns key skey (per 32-half), 16 dh at sdh
    const int skey = tid >> 3, sdh = (tid & 7) * 16;
    const int ss = skey & 7, ch0 = (tid & 7) * 2;
    // V staging: thread owns key pair kp (per 32-half), dh block db (8 dh)
    const int kp = tid >> 4, db = tid & 15;
    const int vlc = ((kp >> 2) ^ (db & 3));   // logical chunk low part

    bf16x8 kreg[2][2], vreg[2][2];
    auto load_regs = [&](int k0) {
#pragma unroll
        for (int hh = 0; hh < 2; hh++) {
            const __bf16* kr = kb + (size_t)(k0 + hh * 32 + skey) * 128 + sdh;
            kreg[hh][0] = *(const bf16x8*)&kr[0];
            kreg[hh][1] = *(const bf16x8*)&kr[8];
            const __bf16* vr = vb + (size_t)(k0 + hh * 32 + 2 * kp) * 128 + db * 8;
            vreg[hh][0] = *(const bf16x8*)&vr[0];
            vreg[hh][1] = *(const bf16x8*)&vr[128];
        }
    };

    load_regs(0);

    for (int kt = 0; kt < trips; kt++) {
        const int k0 = kt * 64;
        __syncthreads();   // #1: prior trip's LDS reads done; waits our global loads
#pragma unroll
        for (int hh = 0; hh < 2; hh++) {
            const int row = hh * 32 + skey;   // row&7 == ss
            *(bf16x8*)&Kt[row * 128 + ((ch0 ^ ss) << 3)]       = kreg[hh][0];
            *(bf16x8*)&Kt[row * 128 + (((ch0 + 1) ^ ss) << 3)] = kreg[hh][1];
            const u16x8 pa = __builtin_bit_cast(u16x8, vreg[hh][0]);
            const u16x8 pb = __builtin_bit_cast(u16x8, vreg[hh][1]);
            const int lc = hh * 4 + vlc;
#pragma unroll
            for (int jj = 0; jj < 8; jj++) {
                const int d = db * 8 + jj;
                Vt32[d * 32 + ((lc ^ jj) << 2) + (kp & 3)] =
                    (u32)pa[jj] | ((u32)pb[jj] << 16);
            }
        }
        __syncthreads();   // #2: staging visible
        if (kt + 1 < trips) load_regs(k0 + 64);   // fly under compute

        // S = Q @ K^T : 4 x 16-key tiles
        f32x4 s_acc[4] = {};
#pragma unroll
        for (int nt = 0; nt < 4; nt++) {
            const int krow = nt * 16 + c;
            const int ks = krow & 7;
#pragma unroll
            for (int dc = 0; dc < 4; dc++) {
                const bf16x8 kf =
                    *(const bf16x8*)&Kt[krow * 128 + (((dc * 4 + g) ^ ks) << 3)];
                s_acc[nt] = MFMA16(qf[dc], kf, s_acc[nt]);
            }
        }

        // mask + online softmax (lane holds rows g*4+r, cols nt*16+c)
        float p[4][4], alpha[4];
#pragma unroll
        for (int r = 0; r < 4; r++) {
            const int qrow = q0 + w * 16 + g * 4 + r;
            float sv[4];
#pragma unroll
            for (int nt = 0; nt < 4; nt++)
                sv[nt] = (k0 + nt * 16 + c <= qrow) ? s_acc[nt][r] * inv_scale : -1e30f;
            float rm = fmaxf(fmaxf(sv[0], sv[1]), fmaxf(sv[2], sv[3]));
            rm = fmaxf(rm, __shfl_xor(rm, 1));
            rm = fmaxf(rm, __shfl_xor(rm, 2));
            rm = fmaxf(rm, __shfl_xor(rm, 4));
            rm = fmaxf(rm, __shfl_xor(rm, 8));
            const float mnew = fmaxf(m_run[r], rm);
            alpha[r] = __expf(m_run[r] - mnew);
            float ps = 0.0f;
#pragma unroll
            for (int nt = 0; nt < 4; nt++) {
                p[nt][r] = __expf(sv[nt] - mnew);
                ps += p[nt][r];
            }
            ps += __shfl_xor(ps, 1);
            ps += __shfl_xor(ps, 2);
            ps += __shfl_xor(ps, 4);
            ps += __shfl_xor(ps, 8);
            l_run[r] = alpha[r] * l_run[r] + ps;
            m_run[r] = mnew;
        }
#pragma unroll
        for (int nt2 = 0; nt2 < 8; nt2++)
#pragma unroll
            for (int r = 0; r < 4; r++)
                accO[nt2][r] *= alpha[r];

        // P -> per-wave LDS (chunk-swizzled), no block barrier needed
#pragma unroll
        for (int nt = 0; nt < 4; nt++)
#pragma unroll
            for (int r = 0; r < 4; r++) {
                const int row = g * 4 + r;
                const int cc = (nt * 2 + (c >> 3)) ^ (row & 7);
                Pw[w][row * 64 + (cc << 3) + (c & 7)] = (__bf16)p[nt][r];
            }
        asm volatile("s_waitcnt lgkmcnt(0)" ::: "memory");
        __builtin_amdgcn_sched_barrier(0);

        bf16x8 pf[2];
#pragma unroll
        for (int s2 = 0; s2 < 2; s2++)
            pf[s2] = *(const bf16x8*)&Pw[w][c * 64 + (((s2 * 4 + g) ^ (c & 7)) << 3)];
#pragma unroll
        for (int nt2 = 0; nt2 < 8; nt2++) {
            const int d = nt2 * 16 + c;
#pragma unroll
            for (int s2 = 0; s2 < 2; s2++) {
                const int lc = s2 * 4 + (g ^ ((d >> 3) & 3));
                const bf16x8 vf = *(const bf16x8*)&(
                    (const __bf16*)Vt32)[d * 64 + ((lc ^ (d & 7)) << 3)];
                accO[nt2] = MFMA16(pf[s2], vf, accO[nt2]);
            }
        }
    }

    // epilogue: normalize, store bf16 to ws_attn [4096][2048]
#pragma unroll
    for (int nt2 = 0; nt2 < 8; nt2++)
#pragma unroll
        for (int r = 0; r < 4; r++) {
            const float v = accO[nt2][r] / l_run[r];
            const int row = (bh >> 4) * 1024 + q0 + w * 16 + g * 4 + r;
            const int col = (bh & 15) * 128 + nt2 * 16 + c;
            O[(size_t)row * 2048 + col] = (__bf16)v;
        }
}

// ---------------------------------------------------------------------------
extern "C" void kernel_launch(void* const* d_in, const int* in_sizes, int n_in,
                              void* d_out, int out_size, void* d_ws, size_t ws_size,
                              hipStream_t stream) {
    const float* query       = (const float*)d_in[0];
    const float* key         = (const float*)d_in[1];
    const float* value       = (const float*)d_in[2];
    const float* cache_key   = (const float*)d_in[3];
    const float* cache_value = (const float*)d_in[4];
    const float* Wq = (const float*)d_in[5];
    const float* bq = (const float*)d_in[6];
    const float* Wk = (const float*)d_in[7];
    const float* bk = (const float*)d_in[8];
    const float* Wv = (const float*)d_in[9];
    const float* bv = (const float*)d_in[10];
    const float* Wo = (const float*)d_in[11];
    const float* bo = (const float*)d_in[12];

    float* out   = (float*)d_out;              // [4096][2048] fp32
    float* new_k = out + 8388608;              // [B][H][2048][128] fp32
    float* new_v = out + 25165824;

    // workspace (bf16 elems): q_bf/k_bf/v_bf MUST be contiguous (A-concat)
    __bf16* p = (__bf16*)d_ws;
    __bf16* ws_q    = p; p += 8388608;         // [b][h][1024][128]
    __bf16* ws_attn = p; p += 8388608;         // [4096][2048]
    __bf16* q_bf    = p; p += 8388608;         // A-concat rows 0..4095
    __bf16* k_bf    = p; p += 8388608;         //               4096..8191
    __bf16* v_bf    = p; p += 8388608;         //               8192..12287
    __bf16* wq_bf   = p; p += 4194304;
    __bf16* wk_bf   = p; p += 4194304;
    __bf16* wv_bf   = p; p += 4194304;
    __bf16* wo_bf   = p; p += 4194304;
    __bf16* ck_bf   = p; p += 8388608;         // [b][h][1024][128] head-major
    __bf16* cv_bf   = p;

    static bool s_attr = false;
    if (!s_attr) {
        hipFuncSetAttribute(reinterpret_cast<const void*>(&gemm8<1>),
                            hipFuncAttributeMaxDynamicSharedMemorySize, 147456);
        hipFuncSetAttribute(reinterpret_cast<const void*>(&gemm8<0>),
                            hipFuncAttributeMaxDynamicSharedMemorySize, 147456);
        s_attr = true;
    }

    prep<<<4096, 256, 0, stream>>>(query, key, value, Wq, Wk, Wv, Wo,
                                   cache_key, cache_value, new_k, new_v,
                                   q_bf, k_bf, v_bf, wq_bf, wk_bf, wv_bf, wo_bf,
                                   ck_bf, cv_bf);
    gemm8<1><<<768, 512, 147456, stream>>>(q_bf, wq_bf, wk_bf, wv_bf,
                                           bq, bk, bv, ws_q, new_k, new_v);
    attn_k<<<dim3(16, 16, 4), 256, 0, stream>>>(ws_q, ck_bf, cv_bf, ws_attn);
    gemm8<0><<<256, 512, 147456, stream>>>(ws_attn, wo_bf, nullptr, nullptr,
                                           bo, nullptr, nullptr, out, nullptr, nullptr);
}

// Round 8
// 615.635 us; speedup vs baseline: 1.1646x; 1.1646x over previous
//
#include <hip/hip_runtime.h>
#include <hip/hip_bf16.h>

// ---------------------------------------------------------------------------
// KV-cached MHA, MI355X. Round 8 (= round 7 with the dispatch-map bug fixed):
//  * gemm8, prep: ROUND-4 VERBATIM (best measured: qkv 141us, out ~47us).
//  * attn_k: QBLK=32, 2-wave 128-thread blocks, 2048 blocks = 8/CU
//    (16 waves/CU). r7 BUG: qb map folded 0..31 onto 0..15 (half the q-rows
//    never computed). FIX: bijective balanced map
//      c4=qq&3, m=qq>>2; qb = (m even) ? 4*c4 + m/2 : 31 - 4*c4 - m/2
//    -> every qb 0..31 exactly once; per-CU trip sum = 132 for all CUs;
//    each CU keeps ONE (b,h); each XCD 8 heads = 4MB K/V (L2-resident).
// ---------------------------------------------------------------------------

typedef __bf16 bf16x8 __attribute__((ext_vector_type(8)));
typedef unsigned short u16x8 __attribute__((ext_vector_type(8)));
typedef float  f32x4  __attribute__((ext_vector_type(4)));
typedef unsigned int u32;

#define MFMA16(a, b, c) __builtin_amdgcn_mfma_f32_16x16x32_bf16((a), (b), (c), 0, 0, 0)

__device__ __forceinline__ void async16(__bf16* lds_p, const __bf16* g) {
    __builtin_amdgcn_global_load_lds(
        (__attribute__((address_space(1))) void*)g,
        (__attribute__((address_space(3))) void*)lds_p, 16, 0, 0);
}

// ---------------------------------------------------------------------------
// prep: one grid-stride BW pass (round-4 verbatim).
// ---------------------------------------------------------------------------
__global__ __launch_bounds__(256) void prep(
    const float* __restrict__ q, const float* __restrict__ k, const float* __restrict__ v,
    const float* __restrict__ wq, const float* __restrict__ wk,
    const float* __restrict__ wv, const float* __restrict__ wo,
    const float* __restrict__ ck, const float* __restrict__ cv,
    float* __restrict__ nk, float* __restrict__ nv,
    __bf16* __restrict__ dq, __bf16* __restrict__ dk, __bf16* __restrict__ dv,
    __bf16* __restrict__ dwq, __bf16* __restrict__ dwk,
    __bf16* __restrict__ dwv, __bf16* __restrict__ dwo,
    __bf16* __restrict__ ckb, __bf16* __restrict__ cvb) {
    const int nthreads = gridDim.x * blockDim.x;
    for (int i = blockIdx.x * blockDim.x + threadIdx.x; i < 7340032; i += nthreads) {
        if (i < 2097152) {
            const int sel = i >> 20;
            const int j = i & 1048575;
            const int dh8 = j & 15;
            const int t = (j >> 4) & 1023;
            const int h = (j >> 14) & 15;
            const int b = j >> 18;
            const float* src = sel ? cv : ck;
            float* dst = sel ? nv : nk;
            __bf16* dstb = sel ? cvb : ckb;
            const size_t si = ((size_t)(b << 10) + t) * 2048 + (h << 7) + (dh8 << 3);
            const size_t di = ((size_t)b << 22) + ((size_t)h << 18) + (t << 7) + (dh8 << 3);
            const size_t bi = (((size_t)(b * 16 + h) * 1024 + t) << 7) + (dh8 << 3);
            const f32x4 x0 = *(const f32x4*)&src[si];
            const f32x4 x1 = *(const f32x4*)&src[si + 4];
            *(f32x4*)&dst[di] = x0;
            *(f32x4*)&dst[di + 4] = x1;
            bf16x8 bx;
#pragma unroll
            for (int e = 0; e < 4; e++) {
                bx[e]     = (__bf16)x0[e];
                bx[e + 4] = (__bf16)x1[e];
            }
            *(bf16x8*)&dstb[bi] = bx;
        } else {
            const float* s;
            __bf16* d;
            int off;
            if (i < 5242880) {
                const int ii = i - 2097152;
                const int r = ii >> 20;
                off = ii & 1048575;
                s = (r == 0) ? q : (r == 1) ? k : v;
                d = (r == 0) ? dq : (r == 1) ? dk : dv;
            } else {
                const int ii = i - 5242880;
                const int r = ii >> 19;
                off = ii & 524287;
                s = (r == 0) ? wq : (r == 1) ? wk : (r == 2) ? wv : wo;
                d = (r == 0) ? dwq : (r == 1) ? dwk : (r == 2) ? dwv : dwo;
            }
            const f32x4 x0 = *(const f32x4*)(s + (size_t)off * 8);
            const f32x4 x1 = *(const f32x4*)(s + (size_t)off * 8 + 4);
            bf16x8 o;
#pragma unroll
            for (int j2 = 0; j2 < 4; j2++) {
                o[j2]     = (__bf16)x0[j2];
                o[j2 + 4] = (__bf16)x1[j2];
            }
            *(bf16x8*)(d + (size_t)off * 8) = o;
        }
    }
}

// ---------------------------------------------------------------------------
// 128x256 8-phase GEMM (round-4 verbatim; best measured GEMM config).
// ---------------------------------------------------------------------------
template <int MODE>
__global__ __launch_bounds__(512, 2) void gemm8(
    const __bf16* __restrict__ A,
    const __bf16* __restrict__ W0, const __bf16* __restrict__ W1,
    const __bf16* __restrict__ W2,
    const float* __restrict__ bz0, const float* __restrict__ bz1,
    const float* __restrict__ bz2,
    void* __restrict__ C0, float* __restrict__ C1, float* __restrict__ C2) {
    extern __shared__ __bf16 lds[];
    constexpr int K = 2048;
    const int tid = threadIdx.x;
    const int w = tid >> 6, lane = tid & 63;
    const int wm = w >> 2, wn = w & 3;
    const int g = lane >> 4, c = lane & 15;

    const int lin = blockIdx.x;
    const int nb = lin & 7, mb = lin >> 3;
    const int m0 = mb << 7, n0 = nb << 8;
    const int seg = (MODE == 1) ? (mb >> 5) : 0;
    const __bf16* W = (MODE == 0 || seg == 0) ? W0 : (seg == 1) ? W1 : W2;
    const float* bias = (MODE == 0) ? bz0 : (seg == 0) ? bz0 : (seg == 1) ? bz1 : bz2;

    const __bf16* Ab = A + (size_t)m0 * K;
    const __bf16* Wb = W + (size_t)n0 * K;

    const int srow = lane >> 2;
    const int sch = (lane & 3) ^ (((lane >> 5) & 1) << 1);
    const int foff = c * 32 + ((g ^ ((c >> 3) << 1)) << 3);

    f32x4 acc[4][4] = {};

    auto stgA = [&](int T, int rg) {
#pragma unroll
        for (int u = 0; u < 2; u++) {
            const __bf16* gs = Ab + (size_t)(w * 16 + srow) * K + T * 64 + u * 32 + sch * 8;
            async16(&lds[rg * 24576 + (w * 2 + u) * 512], gs);
        }
    };
    auto stgB = [&](int T, int rg) {
#pragma unroll
        for (int u = 0; u < 4; u++) {
            const int rowblk = 2 * w + (u >> 1), kk = u & 1;
            const __bf16* gs = Wb + (size_t)(rowblk * 16 + srow) * K + T * 64 + kk * 32 + sch * 8;
            async16(&lds[rg * 24576 + 8192 + (w * 4 + u) * 512], gs);
        }
    };

    stgA(0, 0); stgB(0, 0);
    stgA(1, 1); stgB(1, 1);
    asm volatile("s_waitcnt vmcnt(6)" ::: "memory");
    asm volatile("s_barrier" ::: "memory");

    int rg = 0;
    for (int T = 0; T < 32; T++) {
        int rs = rg + 2; if (rs >= 3) rs -= 3;
        const int base = rg * 24576;
        bf16x8 fa[4], fb[4];

#pragma unroll
        for (int mi = 0; mi < 4; mi++)
            fa[mi] = *(const bf16x8*)&lds[base + ((wm * 4 + mi) * 2 + 0) * 512 + foff];
#pragma unroll
        for (int ni = 0; ni < 4; ni++)
            fb[ni] = *(const bf16x8*)&lds[base + 8192 + ((wn * 4 + ni) * 2 + 0) * 512 + foff];
        if (T < 30) stgA(T + 2, rs);
        asm volatile("s_barrier" ::: "memory");
        asm volatile("s_waitcnt lgkmcnt(0)" ::: "memory");
        __builtin_amdgcn_sched_barrier(0);
        __builtin_amdgcn_s_setprio(1);
#pragma unroll
        for (int mi = 0; mi < 4; mi++)
#pragma unroll
            for (int ni = 0; ni < 4; ni++)
                acc[mi][ni] = MFMA16(fa[mi], fb[ni], acc[mi][ni]);
        __builtin_amdgcn_s_setprio(0);
        asm volatile("s_barrier" ::: "memory");

#pragma unroll
        for (int mi = 0; mi < 4; mi++)
            fa[mi] = *(const bf16x8*)&lds[base + ((wm * 4 + mi) * 2 + 1) * 512 + foff];
#pragma unroll
        for (int ni = 0; ni < 4; ni++)
            fb[ni] = *(const bf16x8*)&lds[base + 8192 + ((wn * 4 + ni) * 2 + 1) * 512 + foff];
        if (T < 30) {
            stgB(T + 2, rs);
            asm volatile("s_waitcnt vmcnt(6)" ::: "memory");
        } else {
            asm volatile("s_waitcnt vmcnt(0)" ::: "memory");
        }
        asm volatile("s_barrier" ::: "memory");
        asm volatile("s_waitcnt lgkmcnt(0)" ::: "memory");
        __builtin_amdgcn_sched_barrier(0);
        __builtin_amdgcn_s_setprio(1);
#pragma unroll
        for (int mi = 0; mi < 4; mi++)
#pragma unroll
            for (int ni = 0; ni < 4; ni++)
                acc[mi][ni] = MFMA16(fa[mi], fb[ni], acc[mi][ni]);
        __builtin_amdgcn_s_setprio(0);
        asm volatile("s_barrier" ::: "memory");

        rg = (rg + 1 == 3) ? 0 : rg + 1;
    }

#pragma unroll
    for (int ni = 0; ni < 4; ni++) {
        const int col = n0 + wn * 64 + ni * 16 + c;
        const float bv = bias[col];
        const int h = col >> 7, dh = col & 127;
#pragma unroll
        for (int mi = 0; mi < 4; mi++) {
            const int rowb = m0 + wm * 64 + mi * 16 + g * 4;
#pragma unroll
            for (int r = 0; r < 4; r++) {
                const float v = acc[mi][ni][r] + bv;
                if (MODE == 0) {
                    ((float*)C0)[(size_t)(rowb + r) * 2048 + col] = v;
                } else {
                    const int lrow = (rowb + r) & 4095;
                    const int b = lrow >> 10, t = lrow & 1023;
                    if (seg == 0)
                        ((__bf16*)C0)[(((size_t)(b * 16 + h) * 1024) + t) * 128 + dh] = (__bf16)v;
                    else if (seg == 1)
                        C1[(((size_t)(b * 16 + h) * 2048) + 1024 + t) * 128 + dh] = v;
                    else
                        C2[(((size_t)(b * 16 + h) * 2048) + 1024 + t) * 128 + dh] = v;
                }
            }
        }
    }
}

// ---------------------------------------------------------------------------
// Flash attention: QBLK=32, 2 waves x 16 q-rows, 128-thread blocks,
// 2048 blocks = 8 blocks/CU (16 waves/CU). KVBLK=32. Wave-level compute
// (QK/softmax/PV, Kt/Vt/Pw layouts+swizzles) identical to verified r3.
// Dispatch: xcd=lin&7; j=lin>>3; bh=xcd*8+(j&7); qq=j>>3 (0..31);
//   c4=qq&3, m=qq>>2; qb = (m even) ? 4*c4+m/2 : 31-4*c4-m/2.
// Bijection onto 0..31 (groups {4c,..,4c+3}u{31-4c,..,28-4c} each sum 124);
// a CU's 8 blocks (lin = cu+256*m) share one bh, one xcd, and trips
// summing 132 for every CU. trips = qb+1.
// ---------------------------------------------------------------------------
__global__ __launch_bounds__(128) void attn_k(const __bf16* __restrict__ Qw,
                                              const __bf16* __restrict__ cK,
                                              const __bf16* __restrict__ cV,
                                              __bf16* __restrict__ O) {
    __shared__ __bf16 Kt[32 * 128];     // 8 KB
    __shared__ u32 Vt32[128 * 16];      // 8 KB
    __shared__ __bf16 Pw[2][16 * 32];   // 2 KB

    const int tid = threadIdx.x;
    const int w = tid >> 6;             // 0..1
    const int lane = tid & 63;
    const int g = lane >> 4, c = lane & 15;

    const int lin = blockIdx.x + (blockIdx.y << 4) + (blockIdx.z << 8);
    const int xcd = lin & 7;
    const int j = lin >> 3;
    const int bh = xcd * 8 + (j & 7);
    const int qq = j >> 3;              // 0..31
    const int c4 = qq & 3, m = qq >> 2;
    const int qb = ((m & 1) == 0) ? (c4 * 4 + (m >> 1)) : (31 - c4 * 4 - (m >> 1));
    const int b = bh >> 4, h = bh & 15;
    const int q0 = qb << 5;
    const float inv_scale = 0.08838834764831845f; // 1/sqrt(128)

    const __bf16* qbase = Qw + (((size_t)bh * 1024) + q0 + w * 16) * 128;
    bf16x8 qf[4];
#pragma unroll
    for (int dc = 0; dc < 4; dc++)
        qf[dc] = *(const bf16x8*)&qbase[c * 128 + dc * 32 + g * 8];

    f32x4 accO[8] = {};
    float m_run[4], l_run[4];
#pragma unroll
    for (int r = 0; r < 4; r++) { m_run[r] = -1e30f; l_run[r] = 0.0f; }

    const int trips = qb + 1;
    const __bf16* kb = cK + (size_t)bh * 1024 * 128;
    const __bf16* vb = cV + (size_t)bh * 1024 * 128;

    // K staging (128 thr): thread owns key skey=tid>>2, chunks 4*(tid&3)..+3
    const int skey = tid >> 2, sgrp = tid & 3;
    const int ss = skey & 7;
    // V staging: thread owns key pair kp=tid>>3, dh block dbv=tid&7 (16 dh)
    const int kp = tid >> 3, dbv = tid & 7;

    for (int kt = 0; kt < trips; kt++) {
        const int k0 = kt * 32;
        // K: 4x bf16x8 (32 dh); V: 2 rows x 2x bf16x8 (16 dh each)
        const __bf16* kr = &kb[(size_t)(k0 + skey) * 128 + sgrp * 32];
        const bf16x8 k_a = *(const bf16x8*)&kr[0];
        const bf16x8 k_b = *(const bf16x8*)&kr[8];
        const bf16x8 k_c = *(const bf16x8*)&kr[16];
        const bf16x8 k_d = *(const bf16x8*)&kr[24];
        const __bf16* vr0 = &vb[(size_t)(k0 + 2 * kp) * 128 + dbv * 16];
        const __bf16* vr1 = &vb[(size_t)(k0 + 2 * kp + 1) * 128 + dbv * 16];
        const bf16x8 v0a = *(const bf16x8*)&vr0[0];
        const bf16x8 v0b = *(const bf16x8*)&vr0[8];
        const bf16x8 v1a = *(const bf16x8*)&vr1[0];
        const bf16x8 v1b = *(const bf16x8*)&vr1[8];
        __syncthreads();   // prior iteration's Kt/Vt reads complete
        {
            const int c0 = sgrp * 4;
            *(bf16x8*)&Kt[skey * 128 + (((c0 + 0) ^ ss) << 3)] = k_a;
            *(bf16x8*)&Kt[skey * 128 + (((c0 + 1) ^ ss) << 3)] = k_b;
            *(bf16x8*)&Kt[skey * 128 + (((c0 + 2) ^ ss) << 3)] = k_c;
            *(bf16x8*)&Kt[skey * 128 + (((c0 + 3) ^ ss) << 3)] = k_d;
        }
        {
            const u16x8 a0 = __builtin_bit_cast(u16x8, v0a);
            const u16x8 a1 = __builtin_bit_cast(u16x8, v0b);
            const u16x8 b0 = __builtin_bit_cast(u16x8, v1a);
            const u16x8 b1 = __builtin_bit_cast(u16x8, v1b);
#pragma unroll
            for (int jj = 0; jj < 8; jj++) {
                const int d0 = dbv * 16 + jj;
                const int d1 = dbv * 16 + 8 + jj;
                const int pc0 = (((kp >> 2) ^ ((d0 >> 3) & 3)) << 2) | (kp & 3);
                const int pc1 = (((kp >> 2) ^ ((d1 >> 3) & 3)) << 2) | (kp & 3);
                Vt32[d0 * 16 + pc0] = (u32)a0[jj] | ((u32)b0[jj] << 16);
                Vt32[d1 * 16 + pc1] = (u32)a1[jj] | ((u32)b1[jj] << 16);
            }
        }
        __syncthreads();   // staging visible

        // S = Q @ K^T  (two 16-key tiles) — r3 verbatim
        f32x4 s_acc[2] = {};
#pragma unroll
        for (int nt = 0; nt < 2; nt++) {
            const int krow = nt * 16 + c;
            const int ks = krow & 7;
#pragma unroll
            for (int dc = 0; dc < 4; dc++) {
                const bf16x8 kf =
                    *(const bf16x8*)&Kt[krow * 128 + (((dc * 4 + g) ^ ks) << 3)];
                s_acc[nt] = MFMA16(qf[dc], kf, s_acc[nt]);
            }
        }

        // mask + online softmax — r3 verbatim
        float p[2][4], alpha[4];
#pragma unroll
        for (int r = 0; r < 4; r++) {
            const int qrow = q0 + w * 16 + g * 4 + r;
            float s0 = (k0 + c      <= qrow) ? s_acc[0][r] * inv_scale : -1e30f;
            float s1 = (k0 + 16 + c <= qrow) ? s_acc[1][r] * inv_scale : -1e30f;
            float rm = fmaxf(s0, s1);
            rm = fmaxf(rm, __shfl_xor(rm, 1));
            rm = fmaxf(rm, __shfl_xor(rm, 2));
            rm = fmaxf(rm, __shfl_xor(rm, 4));
            rm = fmaxf(rm, __shfl_xor(rm, 8));
            const float mnew = fmaxf(m_run[r], rm);
            alpha[r] = __expf(m_run[r] - mnew);
            const float p0 = __expf(s0 - mnew);
            const float p1 = __expf(s1 - mnew);
            p[0][r] = p0; p[1][r] = p1;
            float ps = p0 + p1;
            ps += __shfl_xor(ps, 1);
            ps += __shfl_xor(ps, 2);
            ps += __shfl_xor(ps, 4);
            ps += __shfl_xor(ps, 8);
            l_run[r] = alpha[r] * l_run[r] + ps;
            m_run[r] = mnew;
        }
#pragma unroll
        for (int nt2 = 0; nt2 < 8; nt2++)
#pragma unroll
            for (int r = 0; r < 4; r++)
                accO[nt2][r] *= alpha[r];

        // P -> per-wave LDS (swizzled) — r3 verbatim
#pragma unroll
        for (int nt = 0; nt < 2; nt++)
#pragma unroll
            for (int r = 0; r < 4; r++)
                Pw[w][(g * 4 + r) * 32 + ((((nt << 1) | (c >> 3)) ^ g) << 3) + (c & 7)] =
                    (__bf16)p[nt][r];
        asm volatile("s_waitcnt lgkmcnt(0)" ::: "memory");
        __builtin_amdgcn_sched_barrier(0);

        const bf16x8 pf = *(const bf16x8*)&Pw[w][c * 32 + ((g ^ ((c >> 2) & 3)) << 3)];
#pragma unroll
        for (int nt2 = 0; nt2 < 8; nt2++) {
            const int vrow = nt2 * 16 + c;
            const bf16x8 vf = *(const bf16x8*)&(
                (const __bf16*)Vt32)[vrow * 32 + ((g ^ ((vrow >> 3) & 3)) << 3)];
            accO[nt2] = MFMA16(pf, vf, accO[nt2]);
        }
    }

    // epilogue: normalize, store bf16 to ws_attn [4096][2048]
#pragma unroll
    for (int nt2 = 0; nt2 < 8; nt2++)
#pragma unroll
        for (int r = 0; r < 4; r++) {
            const float v = accO[nt2][r] / l_run[r];
            const int row = b * 1024 + q0 + w * 16 + g * 4 + r;
            const int col = h * 128 + nt2 * 16 + c;
            O[(size_t)row * 2048 + col] = (__bf16)v;
        }
}

// ---------------------------------------------------------------------------
extern "C" void kernel_launch(void* const* d_in, const int* in_sizes, int n_in,
                              void* d_out, int out_size, void* d_ws, size_t ws_size,
                              hipStream_t stream) {
    const float* query       = (const float*)d_in[0];
    const float* key         = (const float*)d_in[1];
    const float* value       = (const float*)d_in[2];
    const float* cache_key   = (const float*)d_in[3];
    const float* cache_value = (const float*)d_in[4];
    const float* Wq = (const float*)d_in[5];
    const float* bq = (const float*)d_in[6];
    const float* Wk = (const float*)d_in[7];
    const float* bk = (const float*)d_in[8];
    const float* Wv = (const float*)d_in[9];
    const float* bv = (const float*)d_in[10];
    const float* Wo = (const float*)d_in[11];
    const float* bo = (const float*)d_in[12];

    float* out   = (float*)d_out;              // [4096][2048] fp32
    float* new_k = out + 8388608;              // [B][H][2048][128] fp32
    float* new_v = out + 25165824;

    // workspace (bf16 elems): q_bf/k_bf/v_bf MUST be contiguous (A-concat)
    __bf16* p = (__bf16*)d_ws;
    __bf16* ws_q    = p; p += 8388608;         // [b][h][1024][128]
    __bf16* ws_attn = p; p += 8388608;         // [4096][2048]
    __bf16* q_bf    = p; p += 8388608;         // A-concat rows 0..4095
    __bf16* k_bf    = p; p += 8388608;         //               4096..8191
    __bf16* v_bf    = p; p += 8388608;         //               8192..12287
    __bf16* wq_bf   = p; p += 4194304;
    __bf16* wk_bf   = p; p += 4194304;
    __bf16* wv_bf   = p; p += 4194304;
    __bf16* wo_bf   = p; p += 4194304;
    __bf16* ck_bf   = p; p += 8388608;         // [b][h][1024][128] head-major
    __bf16* cv_bf   = p;

    static bool s_attr = false;
    if (!s_attr) {
        hipFuncSetAttribute(reinterpret_cast<const void*>(&gemm8<1>),
                            hipFuncAttributeMaxDynamicSharedMemorySize, 147456);
        hipFuncSetAttribute(reinterpret_cast<const void*>(&gemm8<0>),
                            hipFuncAttributeMaxDynamicSharedMemorySize, 147456);
        s_attr = true;
    }

    prep<<<4096, 256, 0, stream>>>(query, key, value, Wq, Wk, Wv, Wo,
                                   cache_key, cache_value, new_k, new_v,
                                   q_bf, k_bf, v_bf, wq_bf, wk_bf, wv_bf, wo_bf,
                                   ck_bf, cv_bf);
    gemm8<1><<<768, 512, 147456, stream>>>(q_bf, wq_bf, wk_bf, wv_bf,
                                           bq, bk, bv, ws_q, new_k, new_v);
    attn_k<<<dim3(16, 16, 8), 128, 0, stream>>>(ws_q, ck_bf, cv_bf, ws_attn);
    gemm8<0><<<256, 512, 147456, stream>>>(ws_attn, wo_bf, nullptr, nullptr,
                                           bo, nullptr, nullptr, out, nullptr, nullptr);
}